// Round 8
// baseline (199.737 us; speedup 1.0000x reference)
//
#include <hip/hip_runtime.h>
#include <hip/hip_bf16.h>

#define THREADS 256
#define FCHUNK 4096
#define HCHUNK 8192
#define BSHIFT 13              // 8192-node dst buckets

typedef _Float16 half8 __attribute__((ext_vector_type(8)));
typedef float f32x4 __attribute__((ext_vector_type(4)));

// ---------- bf16 pack/unpack helpers ----------
__device__ __forceinline__ unsigned pack2(float a, float b) {
    __hip_bfloat16 ba = __float2bfloat16(a);
    __hip_bfloat16 bb = __float2bfloat16(b);
    unsigned short ua, ub;
    __builtin_memcpy(&ua, &ba, 2);
    __builtin_memcpy(&ub, &bb, 2);
    return ((unsigned)ub << 16) | ua;
}
__device__ __forceinline__ unsigned short bf16u(float a) {
    __hip_bfloat16 ba = __float2bfloat16(a);
    unsigned short ua;
    __builtin_memcpy(&ua, &ba, 2);
    return ua;
}
__device__ __forceinline__ float unpack_lo(unsigned u) { return __uint_as_float(u << 16); }
__device__ __forceinline__ float unpack_hi(unsigned u) { return __uint_as_float(u & 0xffff0000u); }

// ================= CSR build =================

__global__ void k_zero(int* __restrict__ p, int n) {
    int i = blockIdx.x * blockDim.x + threadIdx.x;
    if (i < n) p[i] = 0;
}

// bucketed histogram: stage dst chunk in LDS, 7 node-range passes so the
// active count region (32KB) stays L2-resident per pass.
__global__ __launch_bounds__(256) void k_hist_bucket(const int* __restrict__ dst,
                                                     int* __restrict__ count,
                                                     int E, int nbuckets) {
    __shared__ int sdst[HCHUNK];
    int base = blockIdx.x * HCHUNK;
    int cnt = min(HCHUNK, E - base);
    for (int i = threadIdx.x; i < cnt; i += 256) sdst[i] = dst[base + i];
    __syncthreads();
    for (int b = 0; b < nbuckets; ++b) {
        int lo = b << BSHIFT, hi = lo + (1 << BSHIFT);
        for (int i = threadIdx.x; i < cnt; i += 256) {
            int d = sdst[i];
            if (d >= lo && d < hi) atomicAdd(&count[d], 1);
        }
        __syncthreads();
    }
}

__global__ void k_dis(const int* __restrict__ count, float* __restrict__ dis, int n) {
    int i = blockIdx.x * blockDim.x + threadIdx.x;
    if (i < n) dis[i] = rsqrtf((float)(count[i] + 1));
}

__global__ __launch_bounds__(256) void k_scan_local(const int* __restrict__ count,
                                                    int* __restrict__ excl,
                                                    int* __restrict__ bsum, int n) {
    __shared__ int tile[256];
    int i = blockIdx.x * 256 + threadIdx.x;
    int v = (i < n) ? count[i] : 0;
    tile[threadIdx.x] = v;
    __syncthreads();
    for (int off = 1; off < 256; off <<= 1) {
        int add = (threadIdx.x >= off) ? tile[threadIdx.x - off] : 0;
        __syncthreads();
        tile[threadIdx.x] += add;
        __syncthreads();
    }
    if (i < n) excl[i] = tile[threadIdx.x] - v;
    if (threadIdx.x == 255) bsum[blockIdx.x] = tile[255];
}

__global__ __launch_bounds__(256) void k_scan_bsum(int* __restrict__ bsum, int nb) {
    __shared__ int tile[256];
    int v = (threadIdx.x < nb) ? bsum[threadIdx.x] : 0;
    tile[threadIdx.x] = v;
    __syncthreads();
    for (int off = 1; off < 256; off <<= 1) {
        int add = (threadIdx.x >= off) ? tile[threadIdx.x - off] : 0;
        __syncthreads();
        tile[threadIdx.x] += add;
        __syncthreads();
    }
    if (threadIdx.x < nb) bsum[threadIdx.x] = tile[threadIdx.x] - v;
}

__global__ void k_scan_add(const int* __restrict__ excl, const int* __restrict__ bsum,
                           int* __restrict__ rowptr, int* __restrict__ cursor,
                           int n, int E) {
    int i = blockIdx.x * blockDim.x + threadIdx.x;
    if (i < n) {
        int v = excl[i] + bsum[i >> 8];
        rowptr[i] = v;
        cursor[i] = v;
    }
    if (i == 0) rowptr[n] = E;
}

// bucketed fill: stage (src,dst) chunk in LDS, then per node-range pass the
// active col region (~460KB) stays L2-resident -> lines fill before writeback.
__global__ __launch_bounds__(256) void k_fill_bucket(const int* __restrict__ src,
                                                     const int* __restrict__ dst,
                                                     int* __restrict__ cursor,
                                                     int* __restrict__ col,
                                                     int E, int nbuckets) {
    __shared__ int sdst[FCHUNK];
    __shared__ int ssrc[FCHUNK];
    int base = blockIdx.x * FCHUNK;
    int cnt = min(FCHUNK, E - base);
    for (int i = threadIdx.x; i < cnt; i += 256) {
        sdst[i] = dst[base + i];
        ssrc[i] = src[base + i];
    }
    __syncthreads();
    for (int b = 0; b < nbuckets; ++b) {
        int lo = b << BSHIFT, hi = lo + (1 << BSHIFT);
        for (int i = threadIdx.x; i < cnt; i += 256) {
            int d = sdst[i];
            if (d >= lo && d < hi) {
                int pos = atomicAdd(&cursor[d], 1);
                col[pos] = ssrc[i];
            }
        }
        __syncthreads();
    }
}

// ================= MFMA GEMM (f16 in, f32 accum) =========================
// hb[n,128](bf16) = (A[n,128] @ W[128,128]) * dis[row]  (norm pre-folded)

__global__ __launch_bounds__(256) void k_gemm128_mfma(const float* __restrict__ A,
                                                      const float* __restrict__ W,
                                                      const float* __restrict__ dis,
                                                      unsigned short* __restrict__ outb,
                                                      int n) {
    __shared__ _Float16 Wl[16384];   // 32KB, frag-order: slot=(c*4+s)*64+l
    for (int slot = threadIdx.x; slot < 2048; slot += 256) {
        int l = slot & 63;
        int cs = slot >> 6;
        int s = cs & 3, c = cs >> 2;
        int colw = c * 16 + (l & 15);
        int k0 = s * 32 + (l >> 4) * 4;
        const float* wp0 = W + (size_t)k0 * 128 + colw;
        const float* wp1 = wp0 + 16 * 128;
        half8 h;
        h[0] = (_Float16)wp0[0];   h[1] = (_Float16)wp0[128];
        h[2] = (_Float16)wp0[256]; h[3] = (_Float16)wp0[384];
        h[4] = (_Float16)wp1[0];   h[5] = (_Float16)wp1[128];
        h[6] = (_Float16)wp1[256]; h[7] = (_Float16)wp1[384];
        *(half8*)(Wl + (size_t)slot * 8) = h;
    }
    __syncthreads();

    const int l  = threadIdx.x & 63;
    const int wid = threadIdx.x >> 6;
    const int lm = l & 15, q = l >> 4;
    const int rowA = blockIdx.x * 64 + wid * 16 + lm;
    const int ra = (rowA < n) ? rowA : (n - 1);

    f32x4 acc[8];
#pragma unroll
    for (int c = 0; c < 8; ++c) acc[c] = (f32x4){0.f, 0.f, 0.f, 0.f};

#pragma unroll
    for (int s = 0; s < 4; ++s) {
        const float* ap = A + (size_t)ra * 128 + s * 32 + q * 4;
        float4 a0 = *(const float4*)ap;
        float4 a1 = *(const float4*)(ap + 16);
        half8 af;
        af[0] = (_Float16)a0.x; af[1] = (_Float16)a0.y;
        af[2] = (_Float16)a0.z; af[3] = (_Float16)a0.w;
        af[4] = (_Float16)a1.x; af[5] = (_Float16)a1.y;
        af[6] = (_Float16)a1.z; af[7] = (_Float16)a1.w;
#pragma unroll
        for (int c = 0; c < 8; ++c) {
            half8 bf = *(half8*)(Wl + ((size_t)((c * 4 + s) * 64 + l)) * 8);
            acc[c] = __builtin_amdgcn_mfma_f32_16x16x32_f16(af, bf, acc[c], 0, 0, 0);
        }
    }

    const int gr0 = blockIdx.x * 64 + wid * 16 + q * 4;
#pragma unroll
    for (int r = 0; r < 4; ++r) {
        int gr = gr0 + r;
        if (gr >= n) continue;
        float dv = dis[gr];
#pragma unroll
        for (int c = 0; c < 8; ++c)
            outb[(size_t)gr * 128 + c * 16 + lm] = bf16u(acc[c][r] * dv);
    }
}

// ==== MFMA final GEMM: cols 0-63 = Wmu -> mu, cols 64-127 = Wlv -> logvar ===

__global__ __launch_bounds__(256) void k_gemm_out_mfma(const float* __restrict__ A,
                                                       const float* __restrict__ Wmu,
                                                       const float* __restrict__ Wlv,
                                                       const float* __restrict__ bmu,
                                                       const float* __restrict__ blv,
                                                       float* __restrict__ out, int n) {
    __shared__ _Float16 Wl[16384];
    for (int slot = threadIdx.x; slot < 2048; slot += 256) {
        int l = slot & 63;
        int cs = slot >> 6;
        int s = cs & 3, c = cs >> 2;
        int colw = c * 16 + (l & 15);
        const float* Wsrc = (colw < 64) ? Wmu : Wlv;
        int cj = colw & 63;
        int k0 = s * 32 + (l >> 4) * 4;
        const float* wp0 = Wsrc + (size_t)k0 * 64 + cj;
        const float* wp1 = wp0 + 16 * 64;
        half8 h;
        h[0] = (_Float16)wp0[0];   h[1] = (_Float16)wp0[64];
        h[2] = (_Float16)wp0[128]; h[3] = (_Float16)wp0[192];
        h[4] = (_Float16)wp1[0];   h[5] = (_Float16)wp1[64];
        h[6] = (_Float16)wp1[128]; h[7] = (_Float16)wp1[192];
        *(half8*)(Wl + (size_t)slot * 8) = h;
    }
    __syncthreads();

    const int l  = threadIdx.x & 63;
    const int wid = threadIdx.x >> 6;
    const int lm = l & 15, q = l >> 4;
    const int rowA = blockIdx.x * 64 + wid * 16 + lm;
    const int ra = (rowA < n) ? rowA : (n - 1);

    f32x4 acc[8];
#pragma unroll
    for (int c = 0; c < 8; ++c) {
        int colw = c * 16 + lm;
        float bv = (colw < 64) ? bmu[colw] : blv[colw - 64];
        acc[c] = (f32x4){bv, bv, bv, bv};
    }

#pragma unroll
    for (int s = 0; s < 4; ++s) {
        const float* ap = A + (size_t)ra * 128 + s * 32 + q * 4;
        float4 a0 = *(const float4*)ap;
        float4 a1 = *(const float4*)(ap + 16);
        half8 af;
        af[0] = (_Float16)a0.x; af[1] = (_Float16)a0.y;
        af[2] = (_Float16)a0.z; af[3] = (_Float16)a0.w;
        af[4] = (_Float16)a1.x; af[5] = (_Float16)a1.y;
        af[6] = (_Float16)a1.z; af[7] = (_Float16)a1.w;
#pragma unroll
        for (int c = 0; c < 8; ++c) {
            half8 bf = *(half8*)(Wl + ((size_t)((c * 4 + s) * 64 + l)) * 8);
            acc[c] = __builtin_amdgcn_mfma_f32_16x16x32_f16(af, bf, acc[c], 0, 0, 0);
        }
    }

    float* lvp = out + (size_t)n * 64;
    const int gr0 = blockIdx.x * 64 + wid * 16 + q * 4;
#pragma unroll
    for (int r = 0; r < 4; ++r) {
        int gr = gr0 + r;
        if (gr >= n) continue;
#pragma unroll
        for (int c = 0; c < 8; ++c) {
            int colw = c * 16 + lm;
            float v = acc[c][r];
            if (colw < 64) out[(size_t)gr * 64 + colw] = v;
            else           lvp[(size_t)gr * 64 + (colw - 64)] = v;
        }
    }
}

// ================= pre-scaled row-sum gather-aggregate =================
// Rows stored pre-scaled by dis[src]; out = di * (self + sum of src rows).
// One wave per node, quarter-wave per edge; col prefetched 2 deep, rows 1 deep.
// PASS1: r1b = bf16(relu(di*S + b) * di)    PASS2: agg2 = f32(di*T)

template <bool PASS2>
__global__ __launch_bounds__(256) void k_agg(const uint4* __restrict__ hb,
                                             const int* __restrict__ rowptr,
                                             const int* __restrict__ col,
                                             const float* __restrict__ dis,
                                             const float* __restrict__ bias,
                                             uint4* __restrict__ outb,
                                             float* __restrict__ outf, int n) {
    int node = blockIdx.x * 4 + (threadIdx.x >> 6);
    if (node >= n) return;
    int lane = threadIdx.x & 63;
    int q = lane >> 4, l = lane & 15;
    float di = dis[node];

    float acc[8];
#pragma unroll
    for (int c = 0; c < 8; ++c) acc[c] = 0.f;

    int end = rowptr[node + 1];
    int k = rowptr[node] + q;

    // prologue: col 2-deep (s_cur for row issue, s_nxt pending), row 1-deep
    uint4 v0 = {0, 0, 0, 0};
    int s1 = (k + 4 < end) ? col[k + 4] : -1;
    if (k < end) v0 = hb[(size_t)col[k] * 16 + l];

    while (k < end) {
        int s2 = (k + 8 < end) ? col[k + 8] : -1;
        uint4 v1 = {0, 0, 0, 0};
        if (s1 >= 0) v1 = hb[(size_t)s1 * 16 + l];

        acc[0] += unpack_lo(v0.x); acc[1] += unpack_hi(v0.x);
        acc[2] += unpack_lo(v0.y); acc[3] += unpack_hi(v0.y);
        acc[4] += unpack_lo(v0.z); acc[5] += unpack_hi(v0.z);
        acc[6] += unpack_lo(v0.w); acc[7] += unpack_hi(v0.w);

        v0 = v1; s1 = s2; k += 4;
    }

#pragma unroll
    for (int c = 0; c < 8; ++c) acc[c] += __shfl_xor(acc[c], 16);
#pragma unroll
    for (int c = 0; c < 8; ++c) acc[c] += __shfl_xor(acc[c], 32);

    if (q == 0) {
        uint4 sv = hb[(size_t)node * 16 + l];     // self row (pre-scaled)
        acc[0] += unpack_lo(sv.x); acc[1] += unpack_hi(sv.x);
        acc[2] += unpack_lo(sv.y); acc[3] += unpack_hi(sv.y);
        acc[4] += unpack_lo(sv.z); acc[5] += unpack_hi(sv.z);
        acc[6] += unpack_lo(sv.w); acc[7] += unpack_hi(sv.w);
        if (!PASS2) {
            float4 b0 = *(const float4*)(bias + l * 8);
            float4 b1 = *(const float4*)(bias + l * 8 + 4);
            float bv[8] = {b0.x, b0.y, b0.z, b0.w, b1.x, b1.y, b1.z, b1.w};
#pragma unroll
            for (int c = 0; c < 8; ++c)
                acc[c] = fmaxf(acc[c] * di + bv[c], 0.f) * di;
            uint4 o;
            o.x = pack2(acc[0], acc[1]);
            o.y = pack2(acc[2], acc[3]);
            o.z = pack2(acc[4], acc[5]);
            o.w = pack2(acc[6], acc[7]);
            outb[(size_t)node * 16 + l] = o;
        } else {
#pragma unroll
            for (int c = 0; c < 8; ++c) acc[c] *= di;
            float4 o0 = {acc[0], acc[1], acc[2], acc[3]};
            float4 o1 = {acc[4], acc[5], acc[6], acc[7]};
            *(float4*)(outf + (size_t)node * 128 + l * 8)     = o0;
            *(float4*)(outf + (size_t)node * 128 + l * 8 + 4) = o1;
        }
    }
}

// ================= launch =================

extern "C" void kernel_launch(void* const* d_in, const int* in_sizes, int n_in,
                              void* d_out, int out_size, void* d_ws, size_t ws_size,
                              hipStream_t stream) {
    const float* x   = (const float*)d_in[0];
    const int*   ei  = (const int*)d_in[1];
    const float* W1  = (const float*)d_in[2];
    const float* b1  = (const float*)d_in[3];
    const float* Wmu = (const float*)d_in[4];
    const float* bmu = (const float*)d_in[5];
    const float* Wlv = (const float*)d_in[6];
    const float* blv = (const float*)d_in[7];
    float* out = (float*)d_out;

    const int n = in_sizes[0] / 128;   // 50000
    const int E = in_sizes[1] / 2;     // 800000
    const int* src = ei;
    const int* dst = ei + E;

    char* ws = (char*)d_ws;
    float* dis    = (float*)(ws + 0x00000);
    int*   count  = (int*)  (ws + 0x40000);
    int*   rowptr = (int*)  (ws + 0x80000);
    int*   cursor = (int*)  (ws + 0xC0000);
    int*   excl   = (int*)  (ws + 0x100000);
    int*   bsum   = (int*)  (ws + 0x140000);
    int*   col    = (int*)  (ws + 0x180000);            // E ints (3.2MB)
    uint4* h1b    = (uint4*)(ws + 0x580000);            // n*128 bf16 (12.8MB)
    uint4* r1b    = (uint4*)(ws + 0x1200000);           // n*128 bf16 (12.8MB)
    float* agg2   = (float*)(ws + 0x1E40000);           // n*128 f32  (25.6MB)

    const int gN    = (n + THREADS - 1) / THREADS;
    const int gAgg  = (n + 3) / 4;
    const int gGemm = (n + 63) / 64;
    const int nb    = (n + 255) / 256;
    const int nbuck = (n + (1 << BSHIFT) - 1) >> BSHIFT;   // 7
    const int gHist = (E + HCHUNK - 1) / HCHUNK;           // 98
    const int gFill = (E + FCHUNK - 1) / FCHUNK;           // 196

    // CSR build + degrees
    k_zero<<<gN, THREADS, 0, stream>>>(count, n);
    k_hist_bucket<<<gHist, THREADS, 0, stream>>>(dst, count, E, nbuck);
    k_dis <<<gN, THREADS, 0, stream>>>(count, dis, n);
    k_scan_local<<<nb, 256, 0, stream>>>(count, excl, bsum, n);
    k_scan_bsum <<<1, 256, 0, stream>>>(bsum, nb);
    k_scan_add  <<<gN, THREADS, 0, stream>>>(excl, bsum, rowptr, cursor, n, E);
    k_fill_bucket<<<gFill, THREADS, 0, stream>>>(src, dst, cursor, col, E, nbuck);

    // h1b = bf16((x @ W1) * dis)   (f16 MFMA, norm pre-folded)
    k_gemm128_mfma<<<gGemm, THREADS, 0, stream>>>(x, W1, dis, (unsigned short*)h1b, n);

    // r1b = bf16(relu(di*S + b1) * di)
    k_agg<false><<<gAgg, THREADS, 0, stream>>>(h1b, rowptr, col, dis, b1, r1b, nullptr, n);

    // agg2 = di * T   (f32)
    k_agg<true><<<gAgg, THREADS, 0, stream>>>(r1b, rowptr, col, dis, nullptr, nullptr, agg2, n);

    // [mu | logvar] = agg2 @ [Wmu|Wlv] + bias   (f16 MFMA)
    k_gemm_out_mfma<<<gGemm, THREADS, 0, stream>>>(agg2, Wmu, Wlv, bmu, blv, out, n);
}

// Round 9
// 143.667 us; speedup vs baseline: 1.3903x; 1.3903x over previous
//
#include <hip/hip_runtime.h>
#include <hip/hip_bf16.h>

#define THREADS 256
#define PCHUNK 8192            // edges per partition block
#define BN 512                 // nodes per bucket
#define BSH 9

typedef _Float16 half8 __attribute__((ext_vector_type(8)));
typedef float f32x4 __attribute__((ext_vector_type(4)));

// ---------- bf16 pack/unpack helpers ----------
__device__ __forceinline__ unsigned pack2(float a, float b) {
    __hip_bfloat16 ba = __float2bfloat16(a);
    __hip_bfloat16 bb = __float2bfloat16(b);
    unsigned short ua, ub;
    __builtin_memcpy(&ua, &ba, 2);
    __builtin_memcpy(&ub, &bb, 2);
    return ((unsigned)ub << 16) | ua;
}
__device__ __forceinline__ unsigned short bf16u(float a) {
    __hip_bfloat16 ba = __float2bfloat16(a);
    unsigned short ua;
    __builtin_memcpy(&ua, &ba, 2);
    return ua;
}
__device__ __forceinline__ float unpack_lo(unsigned u) { return __uint_as_float(u << 16); }
__device__ __forceinline__ float unpack_hi(unsigned u) { return __uint_as_float(u & 0xffff0000u); }

// ================= CSR build via counting-sort partition =================

// phase 1: per-(block,bucket) histogram; cnt2 layout bucket-major [b][B]
__global__ __launch_bounds__(256) void k_part_count(const int* __restrict__ dst,
                                                    int* __restrict__ cnt2,
                                                    int E, int nbuck, int numBlocks) {
    __shared__ int hist[128];
    for (int i = threadIdx.x; i < nbuck; i += 256) hist[i] = 0;
    __syncthreads();
    int base = blockIdx.x * PCHUNK;
    int cnt = min(PCHUNK, E - base);
    for (int i = threadIdx.x; i < cnt; i += 256)
        atomicAdd(&hist[dst[base + i] >> BSH], 1);
    __syncthreads();
    for (int b = threadIdx.x; b < nbuck; b += 256)
        cnt2[b * numBlocks + blockIdx.x] = hist[b];
}

// ---- 3-stage parallel exclusive scan (generic length) ----
__global__ __launch_bounds__(256) void k_scan_local(const int* __restrict__ count,
                                                    int* __restrict__ excl,
                                                    int* __restrict__ bsum, int n) {
    __shared__ int tile[256];
    int i = blockIdx.x * 256 + threadIdx.x;
    int v = (i < n) ? count[i] : 0;
    tile[threadIdx.x] = v;
    __syncthreads();
    for (int off = 1; off < 256; off <<= 1) {
        int add = (threadIdx.x >= off) ? tile[threadIdx.x - off] : 0;
        __syncthreads();
        tile[threadIdx.x] += add;
        __syncthreads();
    }
    if (i < n) excl[i] = tile[threadIdx.x] - v;
    if (threadIdx.x == 255) bsum[blockIdx.x] = tile[255];
}

__global__ __launch_bounds__(256) void k_scan_bsum(int* __restrict__ bsum, int nb) {
    __shared__ int tile[256];
    int v = (threadIdx.x < nb) ? bsum[threadIdx.x] : 0;
    tile[threadIdx.x] = v;
    __syncthreads();
    for (int off = 1; off < 256; off <<= 1) {
        int add = (threadIdx.x >= off) ? tile[threadIdx.x - off] : 0;
        __syncthreads();
        tile[threadIdx.x] += add;
        __syncthreads();
    }
    if (threadIdx.x < nb) bsum[threadIdx.x] = tile[threadIdx.x] - v;
}

__global__ void k_scan_add2(const int* __restrict__ excl, const int* __restrict__ bsum,
                            int* __restrict__ outv, int m) {
    int i = blockIdx.x * blockDim.x + threadIdx.x;
    if (i < m) outv[i] = excl[i] + bsum[i >> 8];
}

// phase 2: scatter edges into bucket-sorted array; each (block,bucket) range
// is contiguous -> dense coalesced writes.
__global__ __launch_bounds__(256) void k_part_scatter(const int* __restrict__ src,
                                                      const int* __restrict__ dst,
                                                      const int* __restrict__ off,
                                                      int2* __restrict__ sorted,
                                                      int E, int nbuck, int numBlocks) {
    __shared__ int cur[128];
    for (int i = threadIdx.x; i < nbuck; i += 256)
        cur[i] = off[i * numBlocks + blockIdx.x];
    __syncthreads();
    int base = blockIdx.x * PCHUNK;
    int cnt = min(PCHUNK, E - base);
    for (int i = threadIdx.x; i < cnt; i += 256) {
        int d = dst[base + i];
        int s = src[base + i];
        int pos = atomicAdd(&cur[d >> BSH], 1);
        sorted[pos] = make_int2(s, d);
    }
}

// phase 3: one block per bucket builds rowptr/dis/col for its 512 nodes.
// col writes confined to the bucket's contiguous ~32KB range, written by
// one block -> lines fill once.
__global__ __launch_bounds__(256) void k_bucket_build(const int2* __restrict__ sorted,
                                                      const int* __restrict__ off,
                                                      int* __restrict__ rowptr,
                                                      float* __restrict__ dis,
                                                      int* __restrict__ col,
                                                      int E, int n, int nbuck, int numBlocks) {
    __shared__ int hist[BN];
    __shared__ int scanv[BN];
    __shared__ int carry;
    const int b = blockIdx.x;
    const int lo = b << BSH;
    const int s = off[b * numBlocks];
    const int e = (b + 1 < nbuck) ? off[(b + 1) * numBlocks] : E;

    for (int i = threadIdx.x; i < BN; i += 256) hist[i] = 0;
    __syncthreads();
    for (int k = s + threadIdx.x; k < e; k += 256)
        atomicAdd(&hist[sorted[k].y - lo], 1);
    __syncthreads();

    // exclusive scan over BN=512 (two 256-tiles with carry)
    if (threadIdx.x == 0) carry = 0;
    __syncthreads();
    for (int t = 0; t < BN / 256; ++t) {
        int i = t * 256 + threadIdx.x;
        int v = hist[i];
        scanv[i] = v;
        __syncthreads();
        for (int o = 1; o < 256; o <<= 1) {
            int add = (threadIdx.x >= o) ? scanv[t * 256 + threadIdx.x - o] : 0;
            __syncthreads();
            scanv[i] += add;
            __syncthreads();
        }
        int incl = scanv[i];
        scanv[i] = carry + incl - v;
        __syncthreads();
        if (threadIdx.x == 255) carry += incl;
        __syncthreads();
    }

    for (int i = threadIdx.x; i < BN; i += 256) {
        int node = lo + i;
        if (node < n) {
            rowptr[node] = s + scanv[i];
            dis[node] = rsqrtf((float)(hist[i] + 1));
        }
    }
    if (b == 0 && threadIdx.x == 0) rowptr[n] = E;
    __syncthreads();

    for (int k = s + threadIdx.x; k < e; k += 256) {
        int2 ed = sorted[k];
        int pos = s + atomicAdd(&scanv[ed.y - lo], 1);
        col[pos] = ed.x;
    }
}

// ================= MFMA GEMM (f16 in, f32 accum) =========================
// hb[n,128](bf16) = (A[n,128] @ W[128,128]) * dis[row]  (norm pre-folded)

__global__ __launch_bounds__(256) void k_gemm128_mfma(const float* __restrict__ A,
                                                      const float* __restrict__ W,
                                                      const float* __restrict__ dis,
                                                      unsigned short* __restrict__ outb,
                                                      int n) {
    __shared__ _Float16 Wl[16384];   // 32KB, frag-order: slot=(c*4+s)*64+l
    for (int slot = threadIdx.x; slot < 2048; slot += 256) {
        int l = slot & 63;
        int cs = slot >> 6;
        int s = cs & 3, c = cs >> 2;
        int colw = c * 16 + (l & 15);
        int k0 = s * 32 + (l >> 4) * 4;
        const float* wp0 = W + (size_t)k0 * 128 + colw;
        const float* wp1 = wp0 + 16 * 128;
        half8 h;
        h[0] = (_Float16)wp0[0];   h[1] = (_Float16)wp0[128];
        h[2] = (_Float16)wp0[256]; h[3] = (_Float16)wp0[384];
        h[4] = (_Float16)wp1[0];   h[5] = (_Float16)wp1[128];
        h[6] = (_Float16)wp1[256]; h[7] = (_Float16)wp1[384];
        *(half8*)(Wl + (size_t)slot * 8) = h;
    }
    __syncthreads();

    const int l  = threadIdx.x & 63;
    const int wid = threadIdx.x >> 6;
    const int lm = l & 15, q = l >> 4;
    const int rowA = blockIdx.x * 64 + wid * 16 + lm;
    const int ra = (rowA < n) ? rowA : (n - 1);

    f32x4 acc[8];
#pragma unroll
    for (int c = 0; c < 8; ++c) acc[c] = (f32x4){0.f, 0.f, 0.f, 0.f};

#pragma unroll
    for (int s = 0; s < 4; ++s) {
        const float* ap = A + (size_t)ra * 128 + s * 32 + q * 4;
        float4 a0 = *(const float4*)ap;
        float4 a1 = *(const float4*)(ap + 16);
        half8 af;
        af[0] = (_Float16)a0.x; af[1] = (_Float16)a0.y;
        af[2] = (_Float16)a0.z; af[3] = (_Float16)a0.w;
        af[4] = (_Float16)a1.x; af[5] = (_Float16)a1.y;
        af[6] = (_Float16)a1.z; af[7] = (_Float16)a1.w;
#pragma unroll
        for (int c = 0; c < 8; ++c) {
            half8 bf = *(half8*)(Wl + ((size_t)((c * 4 + s) * 64 + l)) * 8);
            acc[c] = __builtin_amdgcn_mfma_f32_16x16x32_f16(af, bf, acc[c], 0, 0, 0);
        }
    }

    const int gr0 = blockIdx.x * 64 + wid * 16 + q * 4;
#pragma unroll
    for (int r = 0; r < 4; ++r) {
        int gr = gr0 + r;
        if (gr >= n) continue;
        float dv = dis[gr];
#pragma unroll
        for (int c = 0; c < 8; ++c)
            outb[(size_t)gr * 128 + c * 16 + lm] = bf16u(acc[c][r] * dv);
    }
}

// ==== MFMA final GEMM: cols 0-63 = Wmu -> mu, cols 64-127 = Wlv -> logvar ===

__global__ __launch_bounds__(256) void k_gemm_out_mfma(const float* __restrict__ A,
                                                       const float* __restrict__ Wmu,
                                                       const float* __restrict__ Wlv,
                                                       const float* __restrict__ bmu,
                                                       const float* __restrict__ blv,
                                                       float* __restrict__ out, int n) {
    __shared__ _Float16 Wl[16384];
    for (int slot = threadIdx.x; slot < 2048; slot += 256) {
        int l = slot & 63;
        int cs = slot >> 6;
        int s = cs & 3, c = cs >> 2;
        int colw = c * 16 + (l & 15);
        const float* Wsrc = (colw < 64) ? Wmu : Wlv;
        int cj = colw & 63;
        int k0 = s * 32 + (l >> 4) * 4;
        const float* wp0 = Wsrc + (size_t)k0 * 64 + cj;
        const float* wp1 = wp0 + 16 * 64;
        half8 h;
        h[0] = (_Float16)wp0[0];   h[1] = (_Float16)wp0[64];
        h[2] = (_Float16)wp0[128]; h[3] = (_Float16)wp0[192];
        h[4] = (_Float16)wp1[0];   h[5] = (_Float16)wp1[64];
        h[6] = (_Float16)wp1[128]; h[7] = (_Float16)wp1[192];
        *(half8*)(Wl + (size_t)slot * 8) = h;
    }
    __syncthreads();

    const int l  = threadIdx.x & 63;
    const int wid = threadIdx.x >> 6;
    const int lm = l & 15, q = l >> 4;
    const int rowA = blockIdx.x * 64 + wid * 16 + lm;
    const int ra = (rowA < n) ? rowA : (n - 1);

    f32x4 acc[8];
#pragma unroll
    for (int c = 0; c < 8; ++c) {
        int colw = c * 16 + lm;
        float bv = (colw < 64) ? bmu[colw] : blv[colw - 64];
        acc[c] = (f32x4){bv, bv, bv, bv};
    }

#pragma unroll
    for (int s = 0; s < 4; ++s) {
        const float* ap = A + (size_t)ra * 128 + s * 32 + q * 4;
        float4 a0 = *(const float4*)ap;
        float4 a1 = *(const float4*)(ap + 16);
        half8 af;
        af[0] = (_Float16)a0.x; af[1] = (_Float16)a0.y;
        af[2] = (_Float16)a0.z; af[3] = (_Float16)a0.w;
        af[4] = (_Float16)a1.x; af[5] = (_Float16)a1.y;
        af[6] = (_Float16)a1.z; af[7] = (_Float16)a1.w;
#pragma unroll
        for (int c = 0; c < 8; ++c) {
            half8 bf = *(half8*)(Wl + ((size_t)((c * 4 + s) * 64 + l)) * 8);
            acc[c] = __builtin_amdgcn_mfma_f32_16x16x32_f16(af, bf, acc[c], 0, 0, 0);
        }
    }

    float* lvp = out + (size_t)n * 64;
    const int gr0 = blockIdx.x * 64 + wid * 16 + q * 4;
#pragma unroll
    for (int r = 0; r < 4; ++r) {
        int gr = gr0 + r;
        if (gr >= n) continue;
#pragma unroll
        for (int c = 0; c < 8; ++c) {
            int colw = c * 16 + lm;
            float v = acc[c][r];
            if (colw < 64) out[(size_t)gr * 64 + colw] = v;
            else           lvp[(size_t)gr * 64 + (colw - 64)] = v;
        }
    }
}

// ================= pre-scaled row-sum gather-aggregate =================
// Rows stored pre-scaled by dis[src]; out = di * (self + sum of src rows).
// One wave per node, quarter-wave per edge; col prefetched 2 deep, rows 1 deep.

template <bool PASS2>
__global__ __launch_bounds__(256) void k_agg(const uint4* __restrict__ hb,
                                             const int* __restrict__ rowptr,
                                             const int* __restrict__ col,
                                             const float* __restrict__ dis,
                                             const float* __restrict__ bias,
                                             uint4* __restrict__ outb,
                                             float* __restrict__ outf, int n) {
    int node = blockIdx.x * 4 + (threadIdx.x >> 6);
    if (node >= n) return;
    int lane = threadIdx.x & 63;
    int q = lane >> 4, l = lane & 15;
    float di = dis[node];

    float acc[8];
#pragma unroll
    for (int c = 0; c < 8; ++c) acc[c] = 0.f;

    int end = rowptr[node + 1];
    int k = rowptr[node] + q;

    uint4 v0 = {0, 0, 0, 0};
    int s1 = (k + 4 < end) ? col[k + 4] : -1;
    if (k < end) v0 = hb[(size_t)col[k] * 16 + l];

    while (k < end) {
        int s2 = (k + 8 < end) ? col[k + 8] : -1;
        uint4 v1 = {0, 0, 0, 0};
        if (s1 >= 0) v1 = hb[(size_t)s1 * 16 + l];

        acc[0] += unpack_lo(v0.x); acc[1] += unpack_hi(v0.x);
        acc[2] += unpack_lo(v0.y); acc[3] += unpack_hi(v0.y);
        acc[4] += unpack_lo(v0.z); acc[5] += unpack_hi(v0.z);
        acc[6] += unpack_lo(v0.w); acc[7] += unpack_hi(v0.w);

        v0 = v1; s1 = s2; k += 4;
    }

#pragma unroll
    for (int c = 0; c < 8; ++c) acc[c] += __shfl_xor(acc[c], 16);
#pragma unroll
    for (int c = 0; c < 8; ++c) acc[c] += __shfl_xor(acc[c], 32);

    if (q == 0) {
        uint4 sv = hb[(size_t)node * 16 + l];     // self row (pre-scaled)
        acc[0] += unpack_lo(sv.x); acc[1] += unpack_hi(sv.x);
        acc[2] += unpack_lo(sv.y); acc[3] += unpack_hi(sv.y);
        acc[4] += unpack_lo(sv.z); acc[5] += unpack_hi(sv.z);
        acc[6] += unpack_lo(sv.w); acc[7] += unpack_hi(sv.w);
        if (!PASS2) {
            float4 b0 = *(const float4*)(bias + l * 8);
            float4 b1 = *(const float4*)(bias + l * 8 + 4);
            float bv[8] = {b0.x, b0.y, b0.z, b0.w, b1.x, b1.y, b1.z, b1.w};
#pragma unroll
            for (int c = 0; c < 8; ++c)
                acc[c] = fmaxf(acc[c] * di + bv[c], 0.f) * di;
            uint4 o;
            o.x = pack2(acc[0], acc[1]);
            o.y = pack2(acc[2], acc[3]);
            o.z = pack2(acc[4], acc[5]);
            o.w = pack2(acc[6], acc[7]);
            outb[(size_t)node * 16 + l] = o;
        } else {
#pragma unroll
            for (int c = 0; c < 8; ++c) acc[c] *= di;
            float4 o0 = {acc[0], acc[1], acc[2], acc[3]};
            float4 o1 = {acc[4], acc[5], acc[6], acc[7]};
            *(float4*)(outf + (size_t)node * 128 + l * 8)     = o0;
            *(float4*)(outf + (size_t)node * 128 + l * 8 + 4) = o1;
        }
    }
}

// ================= launch =================

extern "C" void kernel_launch(void* const* d_in, const int* in_sizes, int n_in,
                              void* d_out, int out_size, void* d_ws, size_t ws_size,
                              hipStream_t stream) {
    const float* x   = (const float*)d_in[0];
    const int*   ei  = (const int*)d_in[1];
    const float* W1  = (const float*)d_in[2];
    const float* b1  = (const float*)d_in[3];
    const float* Wmu = (const float*)d_in[4];
    const float* bmu = (const float*)d_in[5];
    const float* Wlv = (const float*)d_in[6];
    const float* blv = (const float*)d_in[7];
    float* out = (float*)d_out;

    const int n = in_sizes[0] / 128;   // 50000
    const int E = in_sizes[1] / 2;     // 800000
    const int* src = ei;
    const int* dst = ei + E;

    char* ws = (char*)d_ws;
    float* dis    = (float*)(ws + 0x00000);
    int*   rowptr = (int*)  (ws + 0x40000);
    int*   cnt2   = (int*)  (ws + 0x80000);            // nbuck*pBlocks ints
    int*   cnt2s  = (int*)  (ws + 0xC0000);            // scanned
    int*   excl   = (int*)  (ws + 0x100000);
    int*   bsum   = (int*)  (ws + 0x140000);
    int*   col    = (int*)  (ws + 0x180000);            // E ints (3.2MB)
    uint4* h1b    = (uint4*)(ws + 0x580000);            // n*128 bf16 (12.8MB)
    uint4* r1b    = (uint4*)(ws + 0x1200000);           // n*128 bf16 (12.8MB)
    float* agg2   = (float*)(ws + 0x1E40000);           // n*128 f32  (25.6MB)
    int2*  sorted = (int2*) (ws + 0x1E40000);           // 6.4MB, aliases agg2
                                                        // (sorted dead before agg2 written)

    const int gAgg  = (n + 3) / 4;
    const int gGemm = (n + 63) / 64;
    const int nbuck   = (n + BN - 1) / BN;              // 98
    const int pBlocks = (E + PCHUNK - 1) / PCHUNK;      // 98
    const int m2      = nbuck * pBlocks;                // 9604
    const int gM2     = (m2 + 255) / 256;               // 38

    // CSR build: counting-sort partition (all writes dense)
    k_part_count  <<<pBlocks, THREADS, 0, stream>>>(dst, cnt2, E, nbuck, pBlocks);
    k_scan_local  <<<gM2, THREADS, 0, stream>>>(cnt2, excl, bsum, m2);
    k_scan_bsum   <<<1, THREADS, 0, stream>>>(bsum, gM2);
    k_scan_add2   <<<gM2, THREADS, 0, stream>>>(excl, bsum, cnt2s, m2);
    k_part_scatter<<<pBlocks, THREADS, 0, stream>>>(src, dst, cnt2s, sorted, E, nbuck, pBlocks);
    k_bucket_build<<<nbuck, THREADS, 0, stream>>>(sorted, cnt2s, rowptr, dis, col, E, n, nbuck, pBlocks);

    // h1b = bf16((x @ W1) * dis)   (f16 MFMA, norm pre-folded)
    k_gemm128_mfma<<<gGemm, THREADS, 0, stream>>>(x, W1, dis, (unsigned short*)h1b, n);

    // r1b = bf16(relu(di*S + b1) * di)
    k_agg<false><<<gAgg, THREADS, 0, stream>>>(h1b, rowptr, col, dis, b1, r1b, nullptr, n);

    // agg2 = di * T   (f32)
    k_agg<true><<<gAgg, THREADS, 0, stream>>>(r1b, rowptr, col, dis, nullptr, nullptr, agg2, n);

    // [mu | logvar] = agg2 @ [Wmu|Wlv] + bias   (f16 MFMA)
    k_gemm_out_mfma<<<gGemm, THREADS, 0, stream>>>(agg2, Wmu, Wlv, bmu, blv, out, n);
}

// Round 10
// 138.962 us; speedup vs baseline: 1.4374x; 1.0339x over previous
//
#include <hip/hip_runtime.h>
#include <hip/hip_bf16.h>

#define THREADS 256
#define PCHUNK 8192            // edges per partition block
#define BN 512                 // nodes per bucket
#define BSH 9

typedef _Float16 half8 __attribute__((ext_vector_type(8)));
typedef short bf16x8 __attribute__((ext_vector_type(8)));
typedef float f32x4 __attribute__((ext_vector_type(4)));

// ---------- bf16 pack/unpack helpers ----------
__device__ __forceinline__ unsigned pack2(float a, float b) {
    __hip_bfloat16 ba = __float2bfloat16(a);
    __hip_bfloat16 bb = __float2bfloat16(b);
    unsigned short ua, ub;
    __builtin_memcpy(&ua, &ba, 2);
    __builtin_memcpy(&ub, &bb, 2);
    return ((unsigned)ub << 16) | ua;
}
__device__ __forceinline__ unsigned short bf16u(float a) {
    __hip_bfloat16 ba = __float2bfloat16(a);
    unsigned short ua;
    __builtin_memcpy(&ua, &ba, 2);
    return ua;
}
__device__ __forceinline__ float unpack_lo(unsigned u) { return __uint_as_float(u << 16); }
__device__ __forceinline__ float unpack_hi(unsigned u) { return __uint_as_float(u & 0xffff0000u); }

// ================= CSR build via counting-sort partition =================

// phase 1: per-(block,bucket) histogram; cnt2 layout bucket-major [b][B]
__global__ __launch_bounds__(256) void k_part_count(const int* __restrict__ dst,
                                                    int* __restrict__ cnt2,
                                                    int E, int nbuck, int numBlocks) {
    __shared__ int hist[128];
    for (int i = threadIdx.x; i < nbuck; i += 256) hist[i] = 0;
    __syncthreads();
    int base = blockIdx.x * PCHUNK;
    int cnt = min(PCHUNK, E - base);
    for (int i = threadIdx.x; i < cnt; i += 256)
        atomicAdd(&hist[dst[base + i] >> BSH], 1);
    __syncthreads();
    for (int b = threadIdx.x; b < nbuck; b += 256)
        cnt2[b * numBlocks + blockIdx.x] = hist[b];
}

// ---- parallel exclusive scan (3 stages, add fused into consumers) ----
__global__ __launch_bounds__(256) void k_scan_local(const int* __restrict__ count,
                                                    int* __restrict__ excl,
                                                    int* __restrict__ bsum, int n) {
    __shared__ int tile[256];
    int i = blockIdx.x * 256 + threadIdx.x;
    int v = (i < n) ? count[i] : 0;
    tile[threadIdx.x] = v;
    __syncthreads();
    for (int off = 1; off < 256; off <<= 1) {
        int add = (threadIdx.x >= off) ? tile[threadIdx.x - off] : 0;
        __syncthreads();
        tile[threadIdx.x] += add;
        __syncthreads();
    }
    if (i < n) excl[i] = tile[threadIdx.x] - v;
    if (threadIdx.x == 255) bsum[blockIdx.x] = tile[255];
}

__global__ __launch_bounds__(256) void k_scan_bsum(int* __restrict__ bsum, int nb) {
    __shared__ int tile[256];
    int v = (threadIdx.x < nb) ? bsum[threadIdx.x] : 0;
    tile[threadIdx.x] = v;
    __syncthreads();
    for (int off = 1; off < 256; off <<= 1) {
        int add = (threadIdx.x >= off) ? tile[threadIdx.x - off] : 0;
        __syncthreads();
        tile[threadIdx.x] += add;
        __syncthreads();
    }
    if (threadIdx.x < nb) bsum[threadIdx.x] = tile[threadIdx.x] - v;
}

__device__ __forceinline__ int scan_off(const int* excl, const int* bsum, int idx) {
    return excl[idx] + bsum[idx >> 8];
}

// phase 2: scatter edges into bucket-sorted array, packed (src<<9)|(dst&511).
__global__ __launch_bounds__(256) void k_part_scatter(const int* __restrict__ src,
                                                      const int* __restrict__ dst,
                                                      const int* __restrict__ excl,
                                                      const int* __restrict__ bsum,
                                                      int* __restrict__ sorted,
                                                      int E, int nbuck, int numBlocks) {
    __shared__ int cur[128];
    for (int i = threadIdx.x; i < nbuck; i += 256)
        cur[i] = scan_off(excl, bsum, i * numBlocks + blockIdx.x);
    __syncthreads();
    int base = blockIdx.x * PCHUNK;
    int cnt = min(PCHUNK, E - base);
    for (int i = threadIdx.x; i < cnt; i += 256) {
        int d = dst[base + i];
        int s = src[base + i];
        int pos = atomicAdd(&cur[d >> BSH], 1);
        sorted[pos] = (s << BSH) | (d & (BN - 1));
    }
}

// phase 3: one block per bucket builds rowptr/dis/col for its 512 nodes.
__global__ __launch_bounds__(256) void k_bucket_build(const int* __restrict__ sorted,
                                                      const int* __restrict__ excl,
                                                      const int* __restrict__ bsum,
                                                      int* __restrict__ rowptr,
                                                      float* __restrict__ dis,
                                                      int* __restrict__ col,
                                                      int E, int n, int nbuck, int numBlocks) {
    __shared__ int hist[BN];
    __shared__ int scanv[BN];
    __shared__ int carry;
    const int b = blockIdx.x;
    const int lo = b << BSH;
    const int s = scan_off(excl, bsum, b * numBlocks);
    const int e = (b + 1 < nbuck) ? scan_off(excl, bsum, (b + 1) * numBlocks) : E;

    for (int i = threadIdx.x; i < BN; i += 256) hist[i] = 0;
    __syncthreads();
    for (int k = s + threadIdx.x; k < e; k += 256)
        atomicAdd(&hist[sorted[k] & (BN - 1)], 1);
    __syncthreads();

    if (threadIdx.x == 0) carry = 0;
    __syncthreads();
    for (int t = 0; t < BN / 256; ++t) {
        int i = t * 256 + threadIdx.x;
        int v = hist[i];
        scanv[i] = v;
        __syncthreads();
        for (int o = 1; o < 256; o <<= 1) {
            int add = (threadIdx.x >= o) ? scanv[t * 256 + threadIdx.x - o] : 0;
            __syncthreads();
            scanv[i] += add;
            __syncthreads();
        }
        int incl = scanv[i];
        scanv[i] = carry + incl - v;
        __syncthreads();
        if (threadIdx.x == 255) carry += incl;
        __syncthreads();
    }

    for (int i = threadIdx.x; i < BN; i += 256) {
        int node = lo + i;
        if (node < n) {
            rowptr[node] = s + scanv[i];
            dis[node] = rsqrtf((float)(hist[i] + 1));
        }
    }
    if (b == 0 && threadIdx.x == 0) rowptr[n] = E;
    __syncthreads();

    for (int k = s + threadIdx.x; k < e; k += 256) {
        int v = sorted[k];
        int pos = s + atomicAdd(&scanv[v & (BN - 1)], 1);
        col[pos] = ((unsigned)v) >> BSH;
    }
}

// ================= MFMA GEMM 1 (f16 in, f32 accum) =======================
// hb[n,128](bf16) = (A[n,128] @ W[128,128]) * dis[row]  (norm pre-folded)

__global__ __launch_bounds__(256) void k_gemm128_mfma(const float* __restrict__ A,
                                                      const float* __restrict__ W,
                                                      const float* __restrict__ dis,
                                                      unsigned short* __restrict__ outb,
                                                      int n) {
    __shared__ _Float16 Wl[16384];   // 32KB, frag-order: slot=(c*4+s)*64+l
    for (int slot = threadIdx.x; slot < 2048; slot += 256) {
        int l = slot & 63;
        int cs = slot >> 6;
        int s = cs & 3, c = cs >> 2;
        int colw = c * 16 + (l & 15);
        int k0 = s * 32 + (l >> 4) * 4;
        const float* wp0 = W + (size_t)k0 * 128 + colw;
        const float* wp1 = wp0 + 16 * 128;
        half8 h;
        h[0] = (_Float16)wp0[0];   h[1] = (_Float16)wp0[128];
        h[2] = (_Float16)wp0[256]; h[3] = (_Float16)wp0[384];
        h[4] = (_Float16)wp1[0];   h[5] = (_Float16)wp1[128];
        h[6] = (_Float16)wp1[256]; h[7] = (_Float16)wp1[384];
        *(half8*)(Wl + (size_t)slot * 8) = h;
    }
    __syncthreads();

    const int l  = threadIdx.x & 63;
    const int wid = threadIdx.x >> 6;
    const int lm = l & 15, q = l >> 4;
    const int rowA = blockIdx.x * 64 + wid * 16 + lm;
    const int ra = (rowA < n) ? rowA : (n - 1);

    f32x4 acc[8];
#pragma unroll
    for (int c = 0; c < 8; ++c) acc[c] = (f32x4){0.f, 0.f, 0.f, 0.f};

#pragma unroll
    for (int s = 0; s < 4; ++s) {
        const float* ap = A + (size_t)ra * 128 + s * 32 + q * 4;
        float4 a0 = *(const float4*)ap;
        float4 a1 = *(const float4*)(ap + 16);
        half8 af;
        af[0] = (_Float16)a0.x; af[1] = (_Float16)a0.y;
        af[2] = (_Float16)a0.z; af[3] = (_Float16)a0.w;
        af[4] = (_Float16)a1.x; af[5] = (_Float16)a1.y;
        af[6] = (_Float16)a1.z; af[7] = (_Float16)a1.w;
#pragma unroll
        for (int c = 0; c < 8; ++c) {
            half8 bf = *(half8*)(Wl + ((size_t)((c * 4 + s) * 64 + l)) * 8);
            acc[c] = __builtin_amdgcn_mfma_f32_16x16x32_f16(af, bf, acc[c], 0, 0, 0);
        }
    }

    const int gr0 = blockIdx.x * 64 + wid * 16 + q * 4;
#pragma unroll
    for (int r = 0; r < 4; ++r) {
        int gr = gr0 + r;
        if (gr >= n) continue;
        float dv = dis[gr];
#pragma unroll
        for (int c = 0; c < 8; ++c)
            outb[(size_t)gr * 128 + c * 16 + lm] = bf16u(acc[c][r] * dv);
    }
}

// ==== final GEMM, bf16 MFMA: A = agg2 (packed bf16), direct fragment loads ==
// cols 0-63 = Wmu -> mu, cols 64-127 = Wlv -> logvar, f32 out

__global__ __launch_bounds__(256) void k_gemm_out_bf16(const unsigned short* __restrict__ Ab,
                                                       const float* __restrict__ Wmu,
                                                       const float* __restrict__ Wlv,
                                                       const float* __restrict__ bmu,
                                                       const float* __restrict__ blv,
                                                       float* __restrict__ out, int n) {
    __shared__ unsigned short Wl[16384];   // 32KB bf16, frag-order
    for (int slot = threadIdx.x; slot < 2048; slot += 256) {
        int l = slot & 63;
        int cs = slot >> 6;
        int s = cs & 3, c = cs >> 2;
        int colw = c * 16 + (l & 15);
        const float* Wsrc = (colw < 64) ? Wmu : Wlv;
        int cj = colw & 63;
        int k0 = s * 32 + (l >> 4) * 4;
        const float* wp0 = Wsrc + (size_t)k0 * 64 + cj;
        const float* wp1 = wp0 + 16 * 64;
        unsigned short h[8];
        h[0] = bf16u(wp0[0]);   h[1] = bf16u(wp0[64]);
        h[2] = bf16u(wp0[128]); h[3] = bf16u(wp0[192]);
        h[4] = bf16u(wp1[0]);   h[5] = bf16u(wp1[64]);
        h[6] = bf16u(wp1[128]); h[7] = bf16u(wp1[192]);
        *(uint4*)(Wl + (size_t)slot * 8) = *(uint4*)h;
    }
    __syncthreads();

    const int l  = threadIdx.x & 63;
    const int wid = threadIdx.x >> 6;
    const int lm = l & 15, q = l >> 4;
    const int rowA = blockIdx.x * 64 + wid * 16 + lm;
    const int ra = (rowA < n) ? rowA : (n - 1);

    f32x4 acc[8];
#pragma unroll
    for (int c = 0; c < 8; ++c) {
        int colw = c * 16 + lm;
        float bv = (colw < 64) ? bmu[colw] : blv[colw - 64];
        acc[c] = (f32x4){bv, bv, bv, bv};
    }

#pragma unroll
    for (int s = 0; s < 4; ++s) {
        // A fragment: k = s*32 + q*4 + {0..3} and +16 -> two 8B loads
        const unsigned short* ap = Ab + (size_t)ra * 128 + s * 32 + q * 4;
        uint2 a0 = *(const uint2*)ap;
        uint2 a1 = *(const uint2*)(ap + 16);
        bf16x8 af;
        __builtin_memcpy(&af, &a0, 8);
        __builtin_memcpy(((char*)&af) + 8, &a1, 8);
#pragma unroll
        for (int c = 0; c < 8; ++c) {
            bf16x8 bf = *(bf16x8*)(Wl + ((size_t)((c * 4 + s) * 64 + l)) * 8);
            acc[c] = __builtin_amdgcn_mfma_f32_16x16x32_bf16(af, bf, acc[c], 0, 0, 0);
        }
    }

    float* lvp = out + (size_t)n * 64;
    const int gr0 = blockIdx.x * 64 + wid * 16 + q * 4;
#pragma unroll
    for (int r = 0; r < 4; ++r) {
        int gr = gr0 + r;
        if (gr >= n) continue;
#pragma unroll
        for (int c = 0; c < 8; ++c) {
            int colw = c * 16 + lm;
            float v = acc[c][r];
            if (colw < 64) out[(size_t)gr * 64 + colw] = v;
            else           lvp[(size_t)gr * 64 + (colw - 64)] = v;
        }
    }
}

// ================= pre-scaled row-sum gather-aggregate =================
// Rows stored pre-scaled by dis[src]; out = di * (self + sum of src rows).
// PASS1: r1b = bf16(relu(di*S + b) * di)    PASS2: agg2b = bf16(di*T)

template <bool PASS2>
__global__ __launch_bounds__(256) void k_agg(const uint4* __restrict__ hb,
                                             const int* __restrict__ rowptr,
                                             const int* __restrict__ col,
                                             const float* __restrict__ dis,
                                             const float* __restrict__ bias,
                                             uint4* __restrict__ outb, int n) {
    int node = blockIdx.x * 4 + (threadIdx.x >> 6);
    if (node >= n) return;
    int lane = threadIdx.x & 63;
    int q = lane >> 4, l = lane & 15;
    float di = dis[node];

    float acc[8];
#pragma unroll
    for (int c = 0; c < 8; ++c) acc[c] = 0.f;

    int end = rowptr[node + 1];
    int k = rowptr[node] + q;

    uint4 v0 = {0, 0, 0, 0};
    int s1 = (k + 4 < end) ? col[k + 4] : -1;
    if (k < end) v0 = hb[(size_t)col[k] * 16 + l];

    while (k < end) {
        int s2 = (k + 8 < end) ? col[k + 8] : -1;
        uint4 v1 = {0, 0, 0, 0};
        if (s1 >= 0) v1 = hb[(size_t)s1 * 16 + l];

        acc[0] += unpack_lo(v0.x); acc[1] += unpack_hi(v0.x);
        acc[2] += unpack_lo(v0.y); acc[3] += unpack_hi(v0.y);
        acc[4] += unpack_lo(v0.z); acc[5] += unpack_hi(v0.z);
        acc[6] += unpack_lo(v0.w); acc[7] += unpack_hi(v0.w);

        v0 = v1; s1 = s2; k += 4;
    }

#pragma unroll
    for (int c = 0; c < 8; ++c) acc[c] += __shfl_xor(acc[c], 16);
#pragma unroll
    for (int c = 0; c < 8; ++c) acc[c] += __shfl_xor(acc[c], 32);

    if (q == 0) {
        uint4 sv = hb[(size_t)node * 16 + l];     // self row (pre-scaled)
        acc[0] += unpack_lo(sv.x); acc[1] += unpack_hi(sv.x);
        acc[2] += unpack_lo(sv.y); acc[3] += unpack_hi(sv.y);
        acc[4] += unpack_lo(sv.z); acc[5] += unpack_hi(sv.z);
        acc[6] += unpack_lo(sv.w); acc[7] += unpack_hi(sv.w);
        if (!PASS2) {
            float4 b0 = *(const float4*)(bias + l * 8);
            float4 b1 = *(const float4*)(bias + l * 8 + 4);
            float bv[8] = {b0.x, b0.y, b0.z, b0.w, b1.x, b1.y, b1.z, b1.w};
#pragma unroll
            for (int c = 0; c < 8; ++c)
                acc[c] = fmaxf(acc[c] * di + bv[c], 0.f) * di;
        } else {
#pragma unroll
            for (int c = 0; c < 8; ++c) acc[c] *= di;
        }
        uint4 o;
        o.x = pack2(acc[0], acc[1]);
        o.y = pack2(acc[2], acc[3]);
        o.z = pack2(acc[4], acc[5]);
        o.w = pack2(acc[6], acc[7]);
        outb[(size_t)node * 16 + l] = o;
    }
}

// ================= launch =================

extern "C" void kernel_launch(void* const* d_in, const int* in_sizes, int n_in,
                              void* d_out, int out_size, void* d_ws, size_t ws_size,
                              hipStream_t stream) {
    const float* x   = (const float*)d_in[0];
    const int*   ei  = (const int*)d_in[1];
    const float* W1  = (const float*)d_in[2];
    const float* b1  = (const float*)d_in[3];
    const float* Wmu = (const float*)d_in[4];
    const float* bmu = (const float*)d_in[5];
    const float* Wlv = (const float*)d_in[6];
    const float* blv = (const float*)d_in[7];
    float* out = (float*)d_out;

    const int n = in_sizes[0] / 128;   // 50000
    const int E = in_sizes[1] / 2;     // 800000
    const int* src = ei;
    const int* dst = ei + E;

    char* ws = (char*)d_ws;
    float* dis    = (float*)(ws + 0x00000);
    int*   rowptr = (int*)  (ws + 0x40000);
    int*   cnt2   = (int*)  (ws + 0x80000);            // nbuck*pBlocks ints
    int*   excl   = (int*)  (ws + 0x100000);
    int*   bsum   = (int*)  (ws + 0x140000);
    int*   col    = (int*)  (ws + 0x180000);            // E ints (3.2MB)
    uint4* h1b    = (uint4*)(ws + 0x580000);            // n*128 bf16 (12.8MB)
    uint4* r1b    = (uint4*)(ws + 0x1200000);           // n*128 bf16 (12.8MB)
    uint4* agg2b  = h1b;                                // reuse: h1b dead after pass 1
    int*   sorted = (int*)  (ws + 0x1E40000);           // E ints (3.2MB), packed

    const int gAgg  = (n + 3) / 4;
    const int gGemm = (n + 63) / 64;
    const int nbuck   = (n + BN - 1) / BN;              // 98
    const int pBlocks = (E + PCHUNK - 1) / PCHUNK;      // 98
    const int m2      = nbuck * pBlocks;                // 9604
    const int gM2     = (m2 + 255) / 256;               // 38

    // CSR build: counting-sort partition (all writes dense)
    k_part_count  <<<pBlocks, THREADS, 0, stream>>>(dst, cnt2, E, nbuck, pBlocks);
    k_scan_local  <<<gM2, THREADS, 0, stream>>>(cnt2, excl, bsum, m2);
    k_scan_bsum   <<<1, THREADS, 0, stream>>>(bsum, gM2);
    k_part_scatter<<<pBlocks, THREADS, 0, stream>>>(src, dst, excl, bsum, sorted, E, nbuck, pBlocks);
    k_bucket_build<<<nbuck, THREADS, 0, stream>>>(sorted, excl, bsum, rowptr, dis, col, E, n, nbuck, pBlocks);

    // h1b = bf16((x @ W1) * dis)   (f16 MFMA, norm pre-folded)
    k_gemm128_mfma<<<gGemm, THREADS, 0, stream>>>(x, W1, dis, (unsigned short*)h1b, n);

    // r1b = bf16(relu(di*S + b1) * di)
    k_agg<false><<<gAgg, THREADS, 0, stream>>>(h1b, rowptr, col, dis, b1, r1b, n);

    // agg2b = bf16(di * T)   (reuses h1b buffer)
    k_agg<true><<<gAgg, THREADS, 0, stream>>>(r1b, rowptr, col, dis, nullptr, agg2b, n);

    // [mu | logvar] = agg2 @ [Wmu|Wlv] + bias   (bf16 MFMA, direct frag loads)
    k_gemm_out_bf16<<<gGemm, THREADS, 0, stream>>>((const unsigned short*)agg2b,
                                                   Wmu, Wlv, bmu, blv, out, n);
}

// Round 11
// 137.578 us; speedup vs baseline: 1.4518x; 1.0101x over previous
//
#include <hip/hip_runtime.h>
#include <hip/hip_bf16.h>

#define THREADS 256
#define PCHUNK 8192            // edges per partition block
#define BN 512                 // nodes per bucket
#define BSH 9

typedef _Float16 half8 __attribute__((ext_vector_type(8)));
typedef short bf16x8 __attribute__((ext_vector_type(8)));
typedef float f32x4 __attribute__((ext_vector_type(4)));

// ---------- bf16 pack/unpack helpers ----------
__device__ __forceinline__ unsigned pack2(float a, float b) {
    __hip_bfloat16 ba = __float2bfloat16(a);
    __hip_bfloat16 bb = __float2bfloat16(b);
    unsigned short ua, ub;
    __builtin_memcpy(&ua, &ba, 2);
    __builtin_memcpy(&ub, &bb, 2);
    return ((unsigned)ub << 16) | ua;
}
__device__ __forceinline__ unsigned short bf16u(float a) {
    __hip_bfloat16 ba = __float2bfloat16(a);
    unsigned short ua;
    __builtin_memcpy(&ua, &ba, 2);
    return ua;
}
__device__ __forceinline__ float unpack_lo(unsigned u) { return __uint_as_float(u << 16); }
__device__ __forceinline__ float unpack_hi(unsigned u) { return __uint_as_float(u & 0xffff0000u); }

// ================= CSR build via counting-sort partition =================

// phase 1: per-(block,bucket) histogram; cnt2 layout bucket-major [b][B]
__global__ __launch_bounds__(256) void k_part_count(const int* __restrict__ dst,
                                                    int* __restrict__ cnt2,
                                                    int E, int nbuck, int numBlocks) {
    __shared__ int hist[128];
    for (int i = threadIdx.x; i < nbuck; i += 256) hist[i] = 0;
    __syncthreads();
    int base = blockIdx.x * PCHUNK;
    int cnt = min(PCHUNK, E - base);
    for (int i = threadIdx.x; i < cnt; i += 256)
        atomicAdd(&hist[dst[base + i] >> BSH], 1);
    __syncthreads();
    for (int b = threadIdx.x; b < nbuck; b += 256)
        cnt2[b * numBlocks + blockIdx.x] = hist[b];
}

// ---- parallel exclusive scan (3 stages, add fused into consumers) ----
__global__ __launch_bounds__(256) void k_scan_local(const int* __restrict__ count,
                                                    int* __restrict__ excl,
                                                    int* __restrict__ bsum, int n) {
    __shared__ int tile[256];
    int i = blockIdx.x * 256 + threadIdx.x;
    int v = (i < n) ? count[i] : 0;
    tile[threadIdx.x] = v;
    __syncthreads();
    for (int off = 1; off < 256; off <<= 1) {
        int add = (threadIdx.x >= off) ? tile[threadIdx.x - off] : 0;
        __syncthreads();
        tile[threadIdx.x] += add;
        __syncthreads();
    }
    if (i < n) excl[i] = tile[threadIdx.x] - v;
    if (threadIdx.x == 255) bsum[blockIdx.x] = tile[255];
}

__global__ __launch_bounds__(256) void k_scan_bsum(int* __restrict__ bsum, int nb) {
    __shared__ int tile[256];
    int v = (threadIdx.x < nb) ? bsum[threadIdx.x] : 0;
    tile[threadIdx.x] = v;
    __syncthreads();
    for (int off = 1; off < 256; off <<= 1) {
        int add = (threadIdx.x >= off) ? tile[threadIdx.x - off] : 0;
        __syncthreads();
        tile[threadIdx.x] += add;
        __syncthreads();
    }
    if (threadIdx.x < nb) bsum[threadIdx.x] = tile[threadIdx.x] - v;
}

__device__ __forceinline__ int scan_off(const int* excl, const int* bsum, int idx) {
    return excl[idx] + bsum[idx >> 8];
}

// phase 2: scatter edges into bucket-sorted array, packed (src<<9)|(dst&511).
__global__ __launch_bounds__(256) void k_part_scatter(const int* __restrict__ src,
                                                      const int* __restrict__ dst,
                                                      const int* __restrict__ excl,
                                                      const int* __restrict__ bsum,
                                                      int* __restrict__ sorted,
                                                      int E, int nbuck, int numBlocks) {
    __shared__ int cur[128];
    for (int i = threadIdx.x; i < nbuck; i += 256)
        cur[i] = scan_off(excl, bsum, i * numBlocks + blockIdx.x);
    __syncthreads();
    int base = blockIdx.x * PCHUNK;
    int cnt = min(PCHUNK, E - base);
    for (int i = threadIdx.x; i < cnt; i += 256) {
        int d = dst[base + i];
        int s = src[base + i];
        int pos = atomicAdd(&cur[d >> BSH], 1);
        sorted[pos] = (s << BSH) | (d & (BN - 1));
    }
}

// phase 3: one block per bucket builds rowptr/dis/col for its 512 nodes.
__global__ __launch_bounds__(256) void k_bucket_build(const int* __restrict__ sorted,
                                                      const int* __restrict__ excl,
                                                      const int* __restrict__ bsum,
                                                      int* __restrict__ rowptr,
                                                      float* __restrict__ dis,
                                                      int* __restrict__ col,
                                                      int E, int n, int nbuck, int numBlocks) {
    __shared__ int hist[BN];
    __shared__ int scanv[BN];
    __shared__ int carry;
    const int b = blockIdx.x;
    const int lo = b << BSH;
    const int s = scan_off(excl, bsum, b * numBlocks);
    const int e = (b + 1 < nbuck) ? scan_off(excl, bsum, (b + 1) * numBlocks) : E;

    for (int i = threadIdx.x; i < BN; i += 256) hist[i] = 0;
    __syncthreads();
    for (int k = s + threadIdx.x; k < e; k += 256)
        atomicAdd(&hist[sorted[k] & (BN - 1)], 1);
    __syncthreads();

    if (threadIdx.x == 0) carry = 0;
    __syncthreads();
    for (int t = 0; t < BN / 256; ++t) {
        int i = t * 256 + threadIdx.x;
        int v = hist[i];
        scanv[i] = v;
        __syncthreads();
        for (int o = 1; o < 256; o <<= 1) {
            int add = (threadIdx.x >= o) ? scanv[t * 256 + threadIdx.x - o] : 0;
            __syncthreads();
            scanv[i] += add;
            __syncthreads();
        }
        int incl = scanv[i];
        scanv[i] = carry + incl - v;
        __syncthreads();
        if (threadIdx.x == 255) carry += incl;
        __syncthreads();
    }

    for (int i = threadIdx.x; i < BN; i += 256) {
        int node = lo + i;
        if (node < n) {
            rowptr[node] = s + scanv[i];
            dis[node] = rsqrtf((float)(hist[i] + 1));
        }
    }
    if (b == 0 && threadIdx.x == 0) rowptr[n] = E;
    __syncthreads();

    for (int k = s + threadIdx.x; k < e; k += 256) {
        int v = sorted[k];
        int pos = s + atomicAdd(&scanv[v & (BN - 1)], 1);
        col[pos] = ((unsigned)v) >> BSH;
    }
}

// ================= MFMA GEMM 1 (f16 in, f32 accum) =======================
// hb[n,128](bf16) = (A[n,128] @ W[128,128]) * dis[row]  (norm pre-folded)

__global__ __launch_bounds__(256) void k_gemm128_mfma(const float* __restrict__ A,
                                                      const float* __restrict__ W,
                                                      const float* __restrict__ dis,
                                                      unsigned short* __restrict__ outb,
                                                      int n) {
    __shared__ _Float16 Wl[16384];   // 32KB, frag-order: slot=(c*4+s)*64+l
    for (int slot = threadIdx.x; slot < 2048; slot += 256) {
        int l = slot & 63;
        int cs = slot >> 6;
        int s = cs & 3, c = cs >> 2;
        int colw = c * 16 + (l & 15);
        int k0 = s * 32 + (l >> 4) * 4;
        const float* wp0 = W + (size_t)k0 * 128 + colw;
        const float* wp1 = wp0 + 16 * 128;
        half8 h;
        h[0] = (_Float16)wp0[0];   h[1] = (_Float16)wp0[128];
        h[2] = (_Float16)wp0[256]; h[3] = (_Float16)wp0[384];
        h[4] = (_Float16)wp1[0];   h[5] = (_Float16)wp1[128];
        h[6] = (_Float16)wp1[256]; h[7] = (_Float16)wp1[384];
        *(half8*)(Wl + (size_t)slot * 8) = h;
    }
    __syncthreads();

    const int l  = threadIdx.x & 63;
    const int wid = threadIdx.x >> 6;
    const int lm = l & 15, q = l >> 4;
    const int rowA = blockIdx.x * 64 + wid * 16 + lm;
    const int ra = (rowA < n) ? rowA : (n - 1);

    f32x4 acc[8];
#pragma unroll
    for (int c = 0; c < 8; ++c) acc[c] = (f32x4){0.f, 0.f, 0.f, 0.f};

#pragma unroll
    for (int s = 0; s < 4; ++s) {
        const float* ap = A + (size_t)ra * 128 + s * 32 + q * 4;
        float4 a0 = *(const float4*)ap;
        float4 a1 = *(const float4*)(ap + 16);
        half8 af;
        af[0] = (_Float16)a0.x; af[1] = (_Float16)a0.y;
        af[2] = (_Float16)a0.z; af[3] = (_Float16)a0.w;
        af[4] = (_Float16)a1.x; af[5] = (_Float16)a1.y;
        af[6] = (_Float16)a1.z; af[7] = (_Float16)a1.w;
#pragma unroll
        for (int c = 0; c < 8; ++c) {
            half8 bf = *(half8*)(Wl + ((size_t)((c * 4 + s) * 64 + l)) * 8);
            acc[c] = __builtin_amdgcn_mfma_f32_16x16x32_f16(af, bf, acc[c], 0, 0, 0);
        }
    }

    const int gr0 = blockIdx.x * 64 + wid * 16 + q * 4;
#pragma unroll
    for (int r = 0; r < 4; ++r) {
        int gr = gr0 + r;
        if (gr >= n) continue;
        float dv = dis[gr];
#pragma unroll
        for (int c = 0; c < 8; ++c)
            outb[(size_t)gr * 128 + c * 16 + lm] = bf16u(acc[c][r] * dv);
    }
}

// ==== final GEMM, bf16 MFMA: A = agg2 (packed bf16), direct fragment loads ==
// cols 0-63 = Wmu -> mu, cols 64-127 = Wlv -> logvar, f32 out

__global__ __launch_bounds__(256) void k_gemm_out_bf16(const unsigned short* __restrict__ Ab,
                                                       const float* __restrict__ Wmu,
                                                       const float* __restrict__ Wlv,
                                                       const float* __restrict__ bmu,
                                                       const float* __restrict__ blv,
                                                       float* __restrict__ out, int n) {
    __shared__ unsigned short Wl[16384];   // 32KB bf16, frag-order
    for (int slot = threadIdx.x; slot < 2048; slot += 256) {
        int l = slot & 63;
        int cs = slot >> 6;
        int s = cs & 3, c = cs >> 2;
        int colw = c * 16 + (l & 15);
        const float* Wsrc = (colw < 64) ? Wmu : Wlv;
        int cj = colw & 63;
        int k0 = s * 32 + (l >> 4) * 4;
        const float* wp0 = Wsrc + (size_t)k0 * 64 + cj;
        const float* wp1 = wp0 + 16 * 64;
        unsigned short h[8];
        h[0] = bf16u(wp0[0]);   h[1] = bf16u(wp0[64]);
        h[2] = bf16u(wp0[128]); h[3] = bf16u(wp0[192]);
        h[4] = bf16u(wp1[0]);   h[5] = bf16u(wp1[64]);
        h[6] = bf16u(wp1[128]); h[7] = bf16u(wp1[192]);
        *(uint4*)(Wl + (size_t)slot * 8) = *(uint4*)h;
    }
    __syncthreads();

    const int l  = threadIdx.x & 63;
    const int wid = threadIdx.x >> 6;
    const int lm = l & 15, q = l >> 4;
    const int rowA = blockIdx.x * 64 + wid * 16 + lm;
    const int ra = (rowA < n) ? rowA : (n - 1);

    f32x4 acc[8];
#pragma unroll
    for (int c = 0; c < 8; ++c) {
        int colw = c * 16 + lm;
        float bv = (colw < 64) ? bmu[colw] : blv[colw - 64];
        acc[c] = (f32x4){bv, bv, bv, bv};
    }

#pragma unroll
    for (int s = 0; s < 4; ++s) {
        const unsigned short* ap = Ab + (size_t)ra * 128 + s * 32 + q * 4;
        uint2 a0 = *(const uint2*)ap;
        uint2 a1 = *(const uint2*)(ap + 16);
        bf16x8 af;
        __builtin_memcpy(&af, &a0, 8);
        __builtin_memcpy(((char*)&af) + 8, &a1, 8);
#pragma unroll
        for (int c = 0; c < 8; ++c) {
            bf16x8 bf = *(bf16x8*)(Wl + ((size_t)((c * 4 + s) * 64 + l)) * 8);
            acc[c] = __builtin_amdgcn_mfma_f32_16x16x32_bf16(af, bf, acc[c], 0, 0, 0);
        }
    }

    float* lvp = out + (size_t)n * 64;
    const int gr0 = blockIdx.x * 64 + wid * 16 + q * 4;
#pragma unroll
    for (int r = 0; r < 4; ++r) {
        int gr = gr0 + r;
        if (gr >= n) continue;
#pragma unroll
        for (int c = 0; c < 8; ++c) {
            int colw = c * 16 + lm;
            float v = acc[c][r];
            if (colw < 64) out[(size_t)gr * 64 + colw] = v;
            else           lvp[(size_t)gr * 64 + (colw - 64)] = v;
        }
    }
}

// ================= pre-scaled row-sum gather-aggregate =================
// Rows stored pre-scaled by dis[src]; out = di * (self + sum of src rows).
// One wave per node, quarter-wave per edge slot. Deep pipeline: 3 rows +
// 4 cols in flight per quarter-wave (12 outstanding row gathers per wave).
// Self-row and bias hoisted into the prologue to overlap the edge loop.
// PASS1: r1b = bf16(relu(di*S + b) * di)    PASS2: agg2b = bf16(di*T)

template <bool PASS2>
__global__ __launch_bounds__(256) void k_agg(const uint4* __restrict__ hb,
                                             const int* __restrict__ rowptr,
                                             const int* __restrict__ col,
                                             const float* __restrict__ dis,
                                             const float* __restrict__ bias,
                                             uint4* __restrict__ outb, int n) {
    int node = blockIdx.x * 4 + (threadIdx.x >> 6);
    if (node >= n) return;
    int lane = threadIdx.x & 63;
    int q = lane >> 4, l = lane & 15;
    float di = dis[node];

    int beg = rowptr[node];
    int end = rowptr[node + 1];

    // hoisted epilogue operands (overlap with the edge loop)
    uint4 sv = {0, 0, 0, 0};
    if (q == 0) sv = hb[(size_t)node * 16 + l];
    float bv[8] = {0.f, 0.f, 0.f, 0.f, 0.f, 0.f, 0.f, 0.f};
    if (!PASS2) {
        float4 b0 = *(const float4*)(bias + l * 8);
        float4 b1 = *(const float4*)(bias + l * 8 + 4);
        bv[0] = b0.x; bv[1] = b0.y; bv[2] = b0.z; bv[3] = b0.w;
        bv[4] = b1.x; bv[5] = b1.y; bv[6] = b1.z; bv[7] = b1.w;
    }

    float acc[8];
#pragma unroll
    for (int c = 0; c < 8; ++c) acc[c] = 0.f;

    int k = beg + q;
    int s0 = (k      < end) ? col[k]      : -1;
    int s1 = (k + 4  < end) ? col[k + 4]  : -1;
    int s2 = (k + 8  < end) ? col[k + 8]  : -1;
    int s3 = (k + 12 < end) ? col[k + 12] : -1;
    uint4 v0 = {0, 0, 0, 0}, v1 = {0, 0, 0, 0}, v2 = {0, 0, 0, 0};
    if (s0 >= 0) v0 = hb[(size_t)s0 * 16 + l];
    if (s1 >= 0) v1 = hb[(size_t)s1 * 16 + l];
    if (s2 >= 0) v2 = hb[(size_t)s2 * 16 + l];

    while (k < end) {
        int s4 = (k + 16 < end) ? col[k + 16] : -1;
        uint4 v3 = {0, 0, 0, 0};
        if (s3 >= 0) v3 = hb[(size_t)s3 * 16 + l];

        acc[0] += unpack_lo(v0.x); acc[1] += unpack_hi(v0.x);
        acc[2] += unpack_lo(v0.y); acc[3] += unpack_hi(v0.y);
        acc[4] += unpack_lo(v0.z); acc[5] += unpack_hi(v0.z);
        acc[6] += unpack_lo(v0.w); acc[7] += unpack_hi(v0.w);

        v0 = v1; v1 = v2; v2 = v3; s3 = s4; k += 4;
    }

#pragma unroll
    for (int c = 0; c < 8; ++c) acc[c] += __shfl_xor(acc[c], 16);
#pragma unroll
    for (int c = 0; c < 8; ++c) acc[c] += __shfl_xor(acc[c], 32);

    if (q == 0) {
        acc[0] += unpack_lo(sv.x); acc[1] += unpack_hi(sv.x);
        acc[2] += unpack_lo(sv.y); acc[3] += unpack_hi(sv.y);
        acc[4] += unpack_lo(sv.z); acc[5] += unpack_hi(sv.z);
        acc[6] += unpack_lo(sv.w); acc[7] += unpack_hi(sv.w);
        if (!PASS2) {
#pragma unroll
            for (int c = 0; c < 8; ++c)
                acc[c] = fmaxf(acc[c] * di + bv[c], 0.f) * di;
        } else {
#pragma unroll
            for (int c = 0; c < 8; ++c) acc[c] *= di;
        }
        uint4 o;
        o.x = pack2(acc[0], acc[1]);
        o.y = pack2(acc[2], acc[3]);
        o.z = pack2(acc[4], acc[5]);
        o.w = pack2(acc[6], acc[7]);
        outb[(size_t)node * 16 + l] = o;
    }
}

// ================= launch =================

extern "C" void kernel_launch(void* const* d_in, const int* in_sizes, int n_in,
                              void* d_out, int out_size, void* d_ws, size_t ws_size,
                              hipStream_t stream) {
    const float* x   = (const float*)d_in[0];
    const int*   ei  = (const int*)d_in[1];
    const float* W1  = (const float*)d_in[2];
    const float* b1  = (const float*)d_in[3];
    const float* Wmu = (const float*)d_in[4];
    const float* bmu = (const float*)d_in[5];
    const float* Wlv = (const float*)d_in[6];
    const float* blv = (const float*)d_in[7];
    float* out = (float*)d_out;

    const int n = in_sizes[0] / 128;   // 50000
    const int E = in_sizes[1] / 2;     // 800000
    const int* src = ei;
    const int* dst = ei + E;

    char* ws = (char*)d_ws;
    float* dis    = (float*)(ws + 0x00000);
    int*   rowptr = (int*)  (ws + 0x40000);
    int*   cnt2   = (int*)  (ws + 0x80000);            // nbuck*pBlocks ints
    int*   excl   = (int*)  (ws + 0x100000);
    int*   bsum   = (int*)  (ws + 0x140000);
    int*   col    = (int*)  (ws + 0x180000);            // E ints (3.2MB)
    uint4* h1b    = (uint4*)(ws + 0x580000);            // n*128 bf16 (12.8MB)
    uint4* r1b    = (uint4*)(ws + 0x1200000);           // n*128 bf16 (12.8MB)
    uint4* agg2b  = h1b;                                // reuse: h1b dead after pass 1
    int*   sorted = (int*)  (ws + 0x1E40000);           // E ints (3.2MB), packed

    const int gAgg  = (n + 3) / 4;
    const int gGemm = (n + 63) / 64;
    const int nbuck   = (n + BN - 1) / BN;              // 98
    const int pBlocks = (E + PCHUNK - 1) / PCHUNK;      // 98
    const int m2      = nbuck * pBlocks;                // 9604
    const int gM2     = (m2 + 255) / 256;               // 38

    // CSR build: counting-sort partition (all writes dense)
    k_part_count  <<<pBlocks, THREADS, 0, stream>>>(dst, cnt2, E, nbuck, pBlocks);
    k_scan_local  <<<gM2, THREADS, 0, stream>>>(cnt2, excl, bsum, m2);
    k_scan_bsum   <<<1, THREADS, 0, stream>>>(bsum, gM2);
    k_part_scatter<<<pBlocks, THREADS, 0, stream>>>(src, dst, excl, bsum, sorted, E, nbuck, pBlocks);
    k_bucket_build<<<nbuck, THREADS, 0, stream>>>(sorted, excl, bsum, rowptr, dis, col, E, n, nbuck, pBlocks);

    // h1b = bf16((x @ W1) * dis)   (f16 MFMA, norm pre-folded)
    k_gemm128_mfma<<<gGemm, THREADS, 0, stream>>>(x, W1, dis, (unsigned short*)h1b, n);

    // r1b = bf16(relu(di*S + b1) * di)
    k_agg<false><<<gAgg, THREADS, 0, stream>>>(h1b, rowptr, col, dis, b1, r1b, n);

    // agg2b = bf16(di * T)   (reuses h1b buffer)
    k_agg<true><<<gAgg, THREADS, 0, stream>>>(r1b, rowptr, col, dis, nullptr, agg2b, n);

    // [mu | logvar] = agg2 @ [Wmu|Wlv] + bias   (bf16 MFMA, direct frag loads)
    k_gemm_out_bf16<<<gGemm, THREADS, 0, stream>>>((const unsigned short*)agg2b,
                                                   Wmu, Wlv, bmu, blv, out, n);
}